// Round 13
// baseline (41.726 us; speedup 1.0000x reference)
//
#include <hip/hip_runtime.h>
#include <hip/hip_bf16.h>

// SparseGCM: 2-layer causal-window GCN on MI355X — split-bf16, fragment-
// contiguous layout, inline-asm depth-4 prefetch MFMA GEMMs, 3-kernel chain:
//   prep_fused -> gemm1_fused (halo + winsum epilogue -> A2F) -> gemm2.
// R13: raw s_barrier (no vmcnt drain) per K-step phase-locks the 4 waves so
// their identical A-streams hit L1/MSHR instead of 4x L2 refetch.
//
// Edges are j->i for j in [i-16,i) per batch, weights normalize to 1.0 ->
// "gather+segment_sum" == 16-wide sliding-window sum. Only outputs i in
// [512,640) matter: layer1 computes i in [496,640).
//
// Precision (R2/R4): single-bf16 fails (correlated L1 errors x16-amplified by
// the L2 window sum). Split v = hi+lo bf16; compute Ahi*Whi + Ahi*Wlo +
// Alo*Whi (3 MFMAs) ~= fp32. Validated R5-R12 (absmax 0.0039).
//
// Perf history: R5 61.2; R6 99.5 (compiler ate reg pipeline); R7 55.8 (asm
// depth-3 + frag layout); R8 49.7 (depth-4 + burst writes); R9 ABORT (mixing
// compiler vmem with in-flight asm loads); R10 47.8 (XCD colocation); R11
// 45.5 (fast tanh + setprio); R12 41.2 (prep2 fused into gemm1 epilogue).

namespace {

constexpr int BQ    = 64;
constexpr int FEATC = 256;
constexpr int M1 = 144;   // layer-1 rows/batch: i in [496,640)
constexpr int M2 = 128;   // layer-2 rows/batch: i in [512,640)

using ushort = unsigned short;
using short8 = __attribute__((ext_vector_type(8))) short;   // 8 bf16
using f32x4  = __attribute__((ext_vector_type(4))) float;

__device__ __forceinline__ ushort f2bf(float f) {  // RNE
  union { float f; unsigned u; } v{f};
  unsigned r = v.u + 0x7FFFu + ((v.u >> 16) & 1u);
  return (ushort)(r >> 16);
}
__device__ __forceinline__ float bf2f(ushort h) {
  union { unsigned u; float f; } v{(unsigned)h << 16};
  return v.f;
}
__device__ __forceinline__ void split2(float v, ushort& hi, ushort& lo) {
  hi = f2bf(v);
  lo = f2bf(v - bf2f(hi));
}
// tanh(x) = 1 - 2/(1 + exp2(2*log2e*x)); exp2/rcp handle the limits.
__device__ __forceinline__ float tanh_fast(float x) {
  const float e = __builtin_amdgcn_exp2f(x * 2.8853900817779268f);
  return 1.0f - 2.0f * __builtin_amdgcn_rcpf(1.0f + e);
}

// Fragment-contiguous layout. Row r, packed k in [0,512) ([self|win] for A,
// [Wself|Wnbr] for W), s = hi(0)/lo(1) (for W: W1/W2). A wave's MFMA fragment
// = contiguous 1KB block at ((rg*16 + kb)*2 + s)*512, lane-linear inside.
__device__ __forceinline__ size_t frag_idx(int row, int k, int s) {
  return ((size_t)(((row >> 4) * 16 + (k >> 5)) * 2 + s)) * 512
       + ((k >> 3) & 3) * 128 + (row & 15) * 8 + (k & 7);
}
// Same, local to one 16-row group (16384-elem block).
__device__ __forceinline__ int lofs(int row_l, int k, int s) {
  return ((k >> 5) * 2 + s) * 512 + ((k >> 3) & 3) * 128 + row_l * 8 + (k & 7);
}

// ---------------------------------------------------------------------------
// prep_fused: blocks [0,576) = prep1 (A1F via LDS burst, XCD-permuted);
//             blocks [576,640) = weight transpose+split.
// ---------------------------------------------------------------------------
__global__ __launch_bounds__(256) void prep_fused(
    const float* __restrict__ x, const float* __restrict__ nodes,
    const float* __restrict__ W1s, const float* __restrict__ W1n,
    const float* __restrict__ W2s, const float* __restrict__ W2n,
    ushort* __restrict__ A1F, ushort* __restrict__ WF1,
    ushort* __restrict__ WF2) {
  __shared__ ushort lds_o[16384];   // one 16-row frag group (32 KB)
  __shared__ float tile[64][65];
  const int blk = blockIdx.x;
  if (blk < 576) {
    const int G = 4 * (blk % 144) + (blk / 144);   // XCD spread permutation
    const int b = G / 9, c = G % 9, f = threadIdx.x;
    const int t0 = c * 16, i0 = 496 + t0;
    const float* nb = nodes + ((size_t)b * 640) * FEATC + f;
    const float* xb = x     + ((size_t)b * 128) * FEATC + f;

    float v[32];
    #pragma unroll
    for (int d = 0; d < 32; ++d) {
      const int i = i0 - 16 + d;
      v[d] = (i < 512) ? nb[(size_t)i * FEATC] : xb[(size_t)(i - 512) * FEATC];
    }
    float win = 0.f;
    #pragma unroll
    for (int d = 0; d < 16; ++d) win += v[d];

    #pragma unroll
    for (int tt = 0; tt < 16; ++tt) {
      ushort hi, lo;
      split2(v[16 + tt], hi, lo);
      lds_o[lofs(tt, f, 0)] = hi;
      lds_o[lofs(tt, f, 1)] = lo;
      split2(win, hi, lo);
      lds_o[lofs(tt, 256 + f, 0)] = hi;
      lds_o[lofs(tt, 256 + f, 1)] = lo;
      win += v[16 + tt] - v[tt];
    }
    __syncthreads();
    ushort* dst = A1F + (size_t)G * 16384;
    #pragma unroll
    for (int it = 0; it < 8; ++it) {
      const int idx = it * 256 + threadIdx.x;
      *(short8*)(dst + idx * 8) = *(const short8*)(lds_o + idx * 8);
    }
  } else {
    const int w = blk - 576;
    const int z = w >> 4, rem = w & 15;
    const int k0 = (rem >> 2) * 64, n0 = (rem & 3) * 64;
    const float* src = (z == 0) ? W1s : (z == 1) ? W1n : (z == 2) ? W2s : W2n;
    ushort* dst = (z < 2) ? WF1 : WF2;
    const int koff = (z & 1) * 256;
    const int c = threadIdx.x & 63, r4 = threadIdx.x >> 6;
    #pragma unroll
    for (int p = 0; p < 16; ++p) {
      const int k = r4 + p * 4;
      tile[k][c] = src[(size_t)(k0 + k) * FEATC + n0 + c];
    }
    __syncthreads();
    #pragma unroll
    for (int p = 0; p < 16; ++p) {
      const int n = r4 + p * 4;
      ushort hi, lo;
      split2(tile[c][n], hi, lo);
      dst[frag_idx(n0 + n, koff + k0 + c, 0)] = hi;   // W1 (hi) slot
      dst[frag_idx(n0 + n, koff + k0 + c, 1)] = lo;   // W2 (lo) slot
    }
  }
}

// ---------------------------------------------------------------------------
// Shared asm helpers (R9 lesson: ONLY asm vmem between first GLOAD and the
// final WAITV(0); all compiler vmem strictly after).
// SBAR: raw s_barrier, NO waitcnt drain — phase-locks waves for L1 sharing.
// ---------------------------------------------------------------------------
#define GLOAD(dst, ptr)                                                      \
  asm volatile("global_load_dwordx4 %0, %1, off"                             \
               : "=v"(dst) : "v"(ptr) : "memory")

#define WAITV(n) do {                                                        \
  asm volatile("s_waitcnt vmcnt(" #n ")" ::: "memory");                      \
  __builtin_amdgcn_sched_barrier(0);                                         \
} while (0)

#define SBAR asm volatile("s_barrier" :::)

#define MF(a, b, c) c = __builtin_amdgcn_mfma_f32_16x16x32_bf16(a, b, c, 0, 0, 0)

// ---------------------------------------------------------------------------
// gemm1_fused: layer-1 GEMM over an 80-row h1 window (16-row halo), winsum
// epilogue emits A2F fragment groups directly. Grid (128, 4): mx2 = 2b+half,
// ny. Wave = one 16-col strip x 80 rows. 16 K-steps of 32; 12 asm loads/step
// (5 A-frag hi/lo pairs + W pair); 4 rotating slots, steady vmcnt(36).
// A-stream identical across the 4 waves -> SBAR keeps them phase-locked.
// ---------------------------------------------------------------------------
struct FJ { short8 a0h, a0l, a1h, a1l, a2h, a2l, a3h, a3l, a4h, a4l, wh, wl; };

#define LOADJ(Q, kb) do {                                                    \
  GLOAD(Q.a0h, bA0 + (kb) * 1024); GLOAD(Q.a0l, bA0 + (kb) * 1024 + 512);    \
  GLOAD(Q.a1h, bA1 + (kb) * 1024); GLOAD(Q.a1l, bA1 + (kb) * 1024 + 512);    \
  GLOAD(Q.a2h, bA2 + (kb) * 1024); GLOAD(Q.a2l, bA2 + (kb) * 1024 + 512);    \
  GLOAD(Q.a3h, bA3 + (kb) * 1024); GLOAD(Q.a3l, bA3 + (kb) * 1024 + 512);    \
  GLOAD(Q.a4h, bA4 + (kb) * 1024); GLOAD(Q.a4l, bA4 + (kb) * 1024 + 512);    \
  GLOAD(Q.wh,  bW  + (kb) * 1024); GLOAD(Q.wl,  bW  + (kb) * 1024 + 512);    \
} while (0)

#define COMPJ(Q) do {                                                        \
  __builtin_amdgcn_s_setprio(1);                                             \
  MF(Q.a0h, Q.wh, acc[0]); MF(Q.a1h, Q.wh, acc[1]); MF(Q.a2h, Q.wh, acc[2]); \
  MF(Q.a3h, Q.wh, acc[3]); MF(Q.a4h, Q.wh, acc[4]);                          \
  MF(Q.a0h, Q.wl, acc[0]); MF(Q.a1h, Q.wl, acc[1]); MF(Q.a2h, Q.wl, acc[2]); \
  MF(Q.a3h, Q.wl, acc[3]); MF(Q.a4h, Q.wl, acc[4]);                          \
  MF(Q.a0l, Q.wh, acc[0]); MF(Q.a1l, Q.wh, acc[1]); MF(Q.a2l, Q.wh, acc[2]); \
  MF(Q.a3l, Q.wh, acc[3]); MF(Q.a4l, Q.wh, acc[4]);                          \
  __builtin_amdgcn_s_setprio(0);                                             \
  __builtin_amdgcn_sched_barrier(0);                                         \
} while (0)

__global__ __launch_bounds__(256, 2) void gemm1_fused(
    const ushort* __restrict__ A, const ushort* __restrict__ W,
    const float* __restrict__ bias, ushort* __restrict__ A2F) {
  __shared__ float hvt[80][68];     // padded: 2-way max on write
  __shared__ ushort outb[16384];    // A2F staging: 32 units x 512

  const int tid = threadIdx.x;
  const int wave = tid >> 6, lane = tid & 63;
  const int lr = lane & 15, kg = lane >> 4;
  const int mx2 = blockIdx.x, ny = blockIdx.y;
  const int b = mx2 >> 1, half = mx2 & 1;
  const int rgA0 = 9 * b + 4 * half;          // first of 5 A row-groups
  const int n0 = ny * 64;
  const int ngw = ny * 4 + wave;              // W col-group for this wave

  const ushort* bA0 = A + (size_t)(rgA0 + 0) * 16384 + lane * 8;
  const ushort* bA1 = A + (size_t)(rgA0 + 1) * 16384 + lane * 8;
  const ushort* bA2 = A + (size_t)(rgA0 + 2) * 16384 + lane * 8;
  const ushort* bA3 = A + (size_t)(rgA0 + 3) * 16384 + lane * 8;
  const ushort* bA4 = A + (size_t)(rgA0 + 4) * 16384 + lane * 8;
  const ushort* bW  = W + (size_t)ngw * 16384 + lane * 8;

  f32x4 acc[5] = {};
  FJ q0, q1, q2, q3;

  LOADJ(q0, 0); LOADJ(q1, 1); LOADJ(q2, 2); LOADJ(q3, 3); SBAR;
  WAITV(36); COMPJ(q0); LOADJ(q0, 4);  SBAR;
  WAITV(36); COMPJ(q1); LOADJ(q1, 5);  SBAR;
  WAITV(36); COMPJ(q2); LOADJ(q2, 6);  SBAR;
  WAITV(36); COMPJ(q3); LOADJ(q3, 7);  SBAR;
  WAITV(36); COMPJ(q0); LOADJ(q0, 8);  SBAR;
  WAITV(36); COMPJ(q1); LOADJ(q1, 9);  SBAR;
  WAITV(36); COMPJ(q2); LOADJ(q2, 10); SBAR;
  WAITV(36); COMPJ(q3); LOADJ(q3, 11); SBAR;
  WAITV(36); COMPJ(q0); LOADJ(q0, 12); SBAR;
  WAITV(36); COMPJ(q1); LOADJ(q1, 13); SBAR;
  WAITV(36); COMPJ(q2); LOADJ(q2, 14); SBAR;
  WAITV(36); COMPJ(q3); LOADJ(q3, 15); SBAR;
  WAITV(36); COMPJ(q0);
  WAITV(24); COMPJ(q1);
  WAITV(12); COMPJ(q2);
  WAITV(0);  COMPJ(q3);

  // ---- epilogue 1: tanh -> LDS f32 tile [80 rows][64 cols] ----
  const float bv = bias[n0 + wave * 16 + lr];
  #pragma unroll
  for (int fr = 0; fr < 5; ++fr)
    #pragma unroll
    for (int r = 0; r < 4; ++r)
      hvt[fr * 16 + kg * 4 + r][wave * 16 + lr] = tanh_fast(acc[fr][r] + bv);
  __syncthreads();

  // ---- epilogue 2: per-column 16-window sums + split -> outb units ----
  {
    const int col = tid & 63, q = tid >> 6;
    float hv[32];
    #pragma unroll
    for (int d = 0; d < 32; ++d) hv[d] = hvt[q * 16 + d][col];
    float win = 0.f;
    #pragma unroll
    for (int d = 0; d < 16; ++d) win += hv[d];

    const int su = ((q * 4 + (col >> 5)) * 2) * 512
                 + ((col >> 3) & 3) * 128 + (col & 7);
    const int wu = ((q * 4 + 2 + (col >> 5)) * 2) * 512
                 + ((col >> 3) & 3) * 128 + (col & 7);
    #pragma unroll
    for (int tt = 0; tt < 16; ++tt) {
      ushort hi, lo;
      split2(hv[16 + tt], hi, lo);
      outb[su + tt * 8]       = hi;
      outb[su + tt * 8 + 512] = lo;
      split2(win, hi, lo);
      outb[wu + tt * 8]       = hi;
      outb[wu + tt * 8 + 512] = lo;
      win += hv[16 + tt] - hv[tt];
    }
  }
  __syncthreads();

  // ---- epilogue 3: burst copy 32 units of 1KB to A2F ----
  const int rg20 = 4 * mx2;
  #pragma unroll
  for (int it = 0; it < 8; ++it) {
    const int lin = it * 2048 + tid * 8;
    const int u = lin >> 9, w = lin & 511;
    const int uq = u >> 3, ukbl = (u >> 1) & 3, us = u & 1;
    const int KB = (ukbl < 2) ? (2 * ny + ukbl) : (8 + 2 * ny + (ukbl - 2));
    const size_t dst = ((size_t)((rg20 + uq) * 16 + KB) * 2 + us) * 512 + w;
    *(short8*)(A2F + dst) = *(const short8*)(outb + lin);
  }
}

// ---------------------------------------------------------------------------
// gemm2: depth-4 asm pipeline, wave tile 32x32, fast tanh, SBAR phase-lock,
// row-major f32 out.
// ---------------------------------------------------------------------------
struct FB { short8 ah0, ah1, al0, al1, b10, b11, b20, b21; };

#define LOADI(Q, tt) do {                                                    \
  GLOAD(Q.ah0, baseA00 + (tt) * 1024);                                       \
  GLOAD(Q.ah1, baseA10 + (tt) * 1024);                                       \
  GLOAD(Q.al0, baseA01 + (tt) * 1024);                                       \
  GLOAD(Q.al1, baseA11 + (tt) * 1024);                                       \
  GLOAD(Q.b10, baseW0h + (tt) * 1024);                                       \
  GLOAD(Q.b11, baseW1h + (tt) * 1024);                                       \
  GLOAD(Q.b20, baseW0l + (tt) * 1024);                                       \
  GLOAD(Q.b21, baseW1l + (tt) * 1024);                                       \
} while (0)

#define COMP(Q) do {                                                         \
  __builtin_amdgcn_s_setprio(1);                                             \
  MF(Q.ah0, Q.b10, acc00); MF(Q.ah0, Q.b11, acc01);                          \
  MF(Q.ah1, Q.b10, acc10); MF(Q.ah1, Q.b11, acc11);                          \
  MF(Q.ah0, Q.b20, acc00); MF(Q.ah0, Q.b21, acc01);                          \
  MF(Q.ah1, Q.b20, acc10); MF(Q.ah1, Q.b21, acc11);                          \
  MF(Q.al0, Q.b10, acc00); MF(Q.al0, Q.b11, acc01);                          \
  MF(Q.al1, Q.b10, acc10); MF(Q.al1, Q.b11, acc11);                          \
  __builtin_amdgcn_s_setprio(0);                                             \
  __builtin_amdgcn_sched_barrier(0);                                         \
} while (0)

__global__ __launch_bounds__(256, 2) void gemm_mfma(
    const ushort* __restrict__ A, const ushort* __restrict__ W,
    const float* __restrict__ bias, float* __restrict__ out) {
  const int t = threadIdx.x;
  const int wave = t >> 6, lane = t & 63;
  const int lr = lane & 15, kg = lane >> 4;
  const int m0 = blockIdx.x * 64 + (wave >> 1) * 32;
  const int n0 = blockIdx.y * 64 + (wave & 1) * 32;
  const int rg0 = m0 >> 4, ng0 = n0 >> 4;

  const ushort* baseA00 = A + ((size_t)((rg0 + 0) * 32 + 0)) * 512 + lane * 8;
  const ushort* baseA01 = A + ((size_t)((rg0 + 0) * 32 + 1)) * 512 + lane * 8;
  const ushort* baseA10 = A + ((size_t)((rg0 + 1) * 32 + 0)) * 512 + lane * 8;
  const ushort* baseA11 = A + ((size_t)((rg0 + 1) * 32 + 1)) * 512 + lane * 8;
  const ushort* baseW0h = W + ((size_t)((ng0 + 0) * 32 + 0)) * 512 + lane * 8;
  const ushort* baseW0l = W + ((size_t)((ng0 + 0) * 32 + 1)) * 512 + lane * 8;
  const ushort* baseW1h = W + ((size_t)((ng0 + 1) * 32 + 0)) * 512 + lane * 8;
  const ushort* baseW1l = W + ((size_t)((ng0 + 1) * 32 + 1)) * 512 + lane * 8;

  f32x4 acc00 = {}, acc01 = {}, acc10 = {}, acc11 = {};
  FB q0, q1, q2, q3, q4;

  LOADI(q0, 0); LOADI(q1, 1); LOADI(q2, 2); LOADI(q3, 3); LOADI(q4, 4); SBAR;
  WAITV(32); COMP(q0); LOADI(q0, 5);  SBAR;
  WAITV(32); COMP(q1); LOADI(q1, 6);  SBAR;
  WAITV(32); COMP(q2); LOADI(q2, 7);  SBAR;
  WAITV(32); COMP(q3); LOADI(q3, 8);  SBAR;
  WAITV(32); COMP(q4); LOADI(q4, 9);  SBAR;
  WAITV(32); COMP(q0); LOADI(q0, 10); SBAR;
  WAITV(32); COMP(q1); LOADI(q1, 11); SBAR;
  WAITV(32); COMP(q2); LOADI(q2, 12); SBAR;
  WAITV(32); COMP(q3); LOADI(q3, 13); SBAR;
  WAITV(32); COMP(q4); LOADI(q4, 14); SBAR;
  WAITV(32); COMP(q0); LOADI(q0, 15); SBAR;
  WAITV(32); COMP(q1);
  WAITV(24); COMP(q2);
  WAITV(16); COMP(q3);
  WAITV(8);  COMP(q4);
  WAITV(0);  COMP(q0);

  const float bv0 = bias[n0 + lr];
  const float bv1 = bias[n0 + 16 + lr];
  auto epi = [&](const f32x4& a, int mt, int nt, float bv) {
    #pragma unroll
    for (int r = 0; r < 4; ++r) {
      const int row = m0 + mt * 16 + kg * 4 + r;
      const int col = n0 + nt * 16 + lr;
      out[(size_t)row * FEATC + col] = tanh_fast(a[r] + bv);
    }
  };
  epi(acc00, 0, 0, bv0);
  epi(acc01, 0, 1, bv1);
  epi(acc10, 1, 0, bv0);
  epi(acc11, 1, 1, bv1);
}

}  // namespace

extern "C" void kernel_launch(void* const* d_in, const int* in_sizes, int n_in,
                              void* d_out, int out_size, void* d_ws, size_t ws_size,
                              hipStream_t stream) {
  const float* x     = (const float*)d_in[0];
  const float* nodes = (const float*)d_in[1];
  // d_in[2] = edge_weight: forward value ew/ew == 1.0 -> unused.
  const float* W1s = (const float*)d_in[3];
  const float* W1n = (const float*)d_in[4];
  const float* b1  = (const float*)d_in[5];
  const float* W2s = (const float*)d_in[6];
  const float* W2n = (const float*)d_in[7];
  const float* b2  = (const float*)d_in[8];
  float* out = (float*)d_out;

  // workspace (ushort): A1F + A2F + WF1 + WF2 = 36.7 MB
  const size_t a1_sz = (size_t)BQ * M1 * 1024;      // 9,437,184
  const size_t a2_sz = (size_t)BQ * M2 * 1024;      // 8,388,608
  const size_t wf_sz = (size_t)16 * 16 * 2 * 512;   // 262,144 per layer
  const size_t need = (a1_sz + a2_sz + 2 * wf_sz) * sizeof(ushort);
  if (ws_size < need) return;

  ushort* p = (ushort*)d_ws;
  ushort* A1F = p; p += a1_sz;
  ushort* A2F = p; p += a2_sz;
  ushort* WF1 = p; p += wf_sz;
  ushort* WF2 = p; p += wf_sz;

  prep_fused<<<640, 256, 0, stream>>>(x, nodes, W1s, W1n, W2s, W2n,
                                      A1F, WF1, WF2);
  gemm1_fused<<<dim3(BQ * 2, FEATC / 64), 256, 0, stream>>>(A1F, WF1, b1, A2F);
  gemm_mfma<<<dim3((BQ * M2) / 64, FEATC / 64), 256, 0, stream>>>(
      A2F, WF2, b2, out);
}

// Round 14
// 37.369 us; speedup vs baseline: 1.1166x; 1.1166x over previous
//
#include <hip/hip_runtime.h>
#include <hip/hip_bf16.h>

// SparseGCM: 2-layer causal-window GCN on MI355X — split-bf16, fragment-
// contiguous layout, 3-kernel chain:
//   prep_fused -> gemm1_fused (LDS-shared A + halo winsum epilogue) -> gemm2.
//
// Edges are j->i for j in [i-16,i) per batch, weights normalize to 1.0 ->
// "gather+segment_sum" == 16-wide sliding-window sum. Only outputs i in
// [512,640) matter: layer1 computes i in [496,640).
//
// Precision (R2/R4): single-bf16 fails (correlated L1 errors x16-amplified by
// the L2 window sum). Split v = hi+lo bf16; compute Ahi*Whi + Ahi*Wlo +
// Alo*Whi (3 MFMAs) ~= fp32. Validated R5-R13 (absmax 0.0039).
//
// Perf history: R5 61.2; R6 99.5; R7 55.8; R8 49.7; R9 ABORT (compiler reg
// loads inside asm-vmcnt region); R10 47.8; R11 45.5; R12 41.2; R13 41.7
// (SBAR phase-lock NEUTRAL -> reverted; waves already locked, and the real
// limit is per-CU VMEM return BW: gemm1's 4 waves each fetched the identical
// 160KB A-stream = 768KB/block). R14: gemm1 stages A into LDS ONCE per block
// via global_load_lds builtin + asm counted vmcnt + raw s_barrier (the
// m201-verified combo), triple-buffered, depth-2 prefetch, one barrier/step,
// never vmcnt(0) mid-loop. W stays per-wave asm 3-slot rotation.

namespace {

constexpr int BQ    = 64;
constexpr int FEATC = 256;
constexpr int M1 = 144;   // layer-1 rows/batch: i in [496,640)
constexpr int M2 = 128;   // layer-2 rows/batch: i in [512,640)

using ushort = unsigned short;
using short8 = __attribute__((ext_vector_type(8))) short;   // 8 bf16
using f32x4  = __attribute__((ext_vector_type(4))) float;

__device__ __forceinline__ ushort f2bf(float f) {  // RNE
  union { float f; unsigned u; } v{f};
  unsigned r = v.u + 0x7FFFu + ((v.u >> 16) & 1u);
  return (ushort)(r >> 16);
}
__device__ __forceinline__ float bf2f(ushort h) {
  union { unsigned u; float f; } v{(unsigned)h << 16};
  return v.f;
}
__device__ __forceinline__ void split2(float v, ushort& hi, ushort& lo) {
  hi = f2bf(v);
  lo = f2bf(v - bf2f(hi));
}
// tanh(x) = 1 - 2/(1 + exp2(2*log2e*x)); exp2/rcp handle the limits.
__device__ __forceinline__ float tanh_fast(float x) {
  const float e = __builtin_amdgcn_exp2f(x * 2.8853900817779268f);
  return 1.0f - 2.0f * __builtin_amdgcn_rcpf(1.0f + e);
}
__device__ __forceinline__ void gl_lds16(const ushort* g, ushort* l) {
  __builtin_amdgcn_global_load_lds(
      (const __attribute__((address_space(1))) void*)g,
      (__attribute__((address_space(3))) void*)l, 16, 0, 0);
}

// Fragment-contiguous layout. Row r, packed k in [0,512) ([self|win] for A,
// [Wself|Wnbr] for W), s = hi(0)/lo(1) (for W: W1/W2). A wave's MFMA fragment
// = contiguous 1KB block at ((rg*16 + kb)*2 + s)*512, lane-linear inside.
__device__ __forceinline__ size_t frag_idx(int row, int k, int s) {
  return ((size_t)(((row >> 4) * 16 + (k >> 5)) * 2 + s)) * 512
       + ((k >> 3) & 3) * 128 + (row & 15) * 8 + (k & 7);
}
// Same, local to one 16-row group (16384-elem block).
__device__ __forceinline__ int lofs(int row_l, int k, int s) {
  return ((k >> 5) * 2 + s) * 512 + ((k >> 3) & 3) * 128 + row_l * 8 + (k & 7);
}

// ---------------------------------------------------------------------------
// prep_fused: blocks [0,576) = prep1 (A1F via LDS burst, XCD-permuted);
//             blocks [576,640) = weight transpose+split.
// ---------------------------------------------------------------------------
__global__ __launch_bounds__(256) void prep_fused(
    const float* __restrict__ x, const float* __restrict__ nodes,
    const float* __restrict__ W1s, const float* __restrict__ W1n,
    const float* __restrict__ W2s, const float* __restrict__ W2n,
    ushort* __restrict__ A1F, ushort* __restrict__ WF1,
    ushort* __restrict__ WF2) {
  __shared__ ushort lds_o[16384];   // one 16-row frag group (32 KB)
  __shared__ float tile[64][65];
  const int blk = blockIdx.x;
  if (blk < 576) {
    const int G = 4 * (blk % 144) + (blk / 144);   // XCD spread permutation
    const int b = G / 9, c = G % 9, f = threadIdx.x;
    const int t0 = c * 16, i0 = 496 + t0;
    const float* nb = nodes + ((size_t)b * 640) * FEATC + f;
    const float* xb = x     + ((size_t)b * 128) * FEATC + f;

    float v[32];
    #pragma unroll
    for (int d = 0; d < 32; ++d) {
      const int i = i0 - 16 + d;
      v[d] = (i < 512) ? nb[(size_t)i * FEATC] : xb[(size_t)(i - 512) * FEATC];
    }
    float win = 0.f;
    #pragma unroll
    for (int d = 0; d < 16; ++d) win += v[d];

    #pragma unroll
    for (int tt = 0; tt < 16; ++tt) {
      ushort hi, lo;
      split2(v[16 + tt], hi, lo);
      lds_o[lofs(tt, f, 0)] = hi;
      lds_o[lofs(tt, f, 1)] = lo;
      split2(win, hi, lo);
      lds_o[lofs(tt, 256 + f, 0)] = hi;
      lds_o[lofs(tt, 256 + f, 1)] = lo;
      win += v[16 + tt] - v[tt];
    }
    __syncthreads();
    ushort* dst = A1F + (size_t)G * 16384;
    #pragma unroll
    for (int it = 0; it < 8; ++it) {
      const int idx = it * 256 + threadIdx.x;
      *(short8*)(dst + idx * 8) = *(const short8*)(lds_o + idx * 8);
    }
  } else {
    const int w = blk - 576;
    const int z = w >> 4, rem = w & 15;
    const int k0 = (rem >> 2) * 64, n0 = (rem & 3) * 64;
    const float* src = (z == 0) ? W1s : (z == 1) ? W1n : (z == 2) ? W2s : W2n;
    ushort* dst = (z < 2) ? WF1 : WF2;
    const int koff = (z & 1) * 256;
    const int c = threadIdx.x & 63, r4 = threadIdx.x >> 6;
    #pragma unroll
    for (int p = 0; p < 16; ++p) {
      const int k = r4 + p * 4;
      tile[k][c] = src[(size_t)(k0 + k) * FEATC + n0 + c];
    }
    __syncthreads();
    #pragma unroll
    for (int p = 0; p < 16; ++p) {
      const int n = r4 + p * 4;
      ushort hi, lo;
      split2(tile[c][n], hi, lo);
      dst[frag_idx(n0 + n, koff + k0 + c, 0)] = hi;   // W1 (hi) slot
      dst[frag_idx(n0 + n, koff + k0 + c, 1)] = lo;   // W2 (lo) slot
    }
  }
}

// ---------------------------------------------------------------------------
// Shared asm helpers. Rules: only asm vmem / gl_lds builtin inside pipelined
// regions; counted vmcnt via asm; raw barrier via builtin (no drain).
// ---------------------------------------------------------------------------
#define GLOAD(dst, ptr)                                                      \
  asm volatile("global_load_dwordx4 %0, %1, off"                             \
               : "=v"(dst) : "v"(ptr) : "memory")

#define WAITV(n) do {                                                        \
  asm volatile("s_waitcnt vmcnt(" #n ")" ::: "memory");                      \
  __builtin_amdgcn_sched_barrier(0);                                         \
} while (0)

#define MF(a, b, c) c = __builtin_amdgcn_mfma_f32_16x16x32_bf16(a, b, c, 0, 0, 0)

// ---------------------------------------------------------------------------
// gemm1_fused: layer-1 GEMM, 80-row h1 window (16-row halo), A staged in LDS
// once per block (10 x 1KB units per K-step; waves 0,1 issue 3 gl_lds each,
// waves 2,3 issue 2). Triple-buffered, staged 2 steps ahead; W per-wave asm
// 3-slot rotation. One raw barrier per step; waits: waves 0,1 vmcnt(5),
// waves 2,3 vmcnt(4) (= own G+2, constant in steady state), vmcnt(0) only at
// the final step. Winsum epilogue emits A2F fragment groups (LDS reused).
// ---------------------------------------------------------------------------
#define STAGEA(jn, kb) do {                                                  \
  gl_lds16(srcu0 + (kb) * 1024, sbase + (jn) * 5120 + u0 * 512);             \
  gl_lds16(srcu1 + (kb) * 1024, sbase + (jn) * 5120 + u1 * 512);             \
  if (g3) gl_lds16(srcu2 + (kb) * 1024, sbase + (jn) * 5120 + u2 * 512);     \
} while (0)

#define WAITW do { if (g3) { WAITV(5); } else { WAITV(4); } } while (0)

#define COMPJ2(j, WH, WL) do {                                               \
  const ushort* bp_ = sbase + (j) * 5120 + lane * 8;                         \
  const short8 a0h = *(const short8*)(bp_ + 0 * 512);                        \
  const short8 a0l = *(const short8*)(bp_ + 1 * 512);                        \
  const short8 a1h = *(const short8*)(bp_ + 2 * 512);                        \
  const short8 a1l = *(const short8*)(bp_ + 3 * 512);                        \
  const short8 a2h = *(const short8*)(bp_ + 4 * 512);                        \
  const short8 a2l = *(const short8*)(bp_ + 5 * 512);                        \
  const short8 a3h = *(const short8*)(bp_ + 6 * 512);                        \
  const short8 a3l = *(const short8*)(bp_ + 7 * 512);                        \
  const short8 a4h = *(const short8*)(bp_ + 8 * 512);                        \
  const short8 a4l = *(const short8*)(bp_ + 9 * 512);                        \
  __builtin_amdgcn_s_setprio(1);                                            \
  MF(a0h, WH, acc[0]); MF(a1h, WH, acc[1]); MF(a2h, WH, acc[2]);             \
  MF(a3h, WH, acc[3]); MF(a4h, WH, acc[4]);                                  \
  MF(a0h, WL, acc[0]); MF(a1h, WL, acc[1]); MF(a2h, WL, acc[2]);             \
  MF(a3h, WL, acc[3]); MF(a4h, WL, acc[4]);                                  \
  MF(a0l, WH, acc[0]); MF(a1l, WH, acc[1]); MF(a2l, WH, acc[2]);             \
  MF(a3l, WH, acc[3]); MF(a4l, WH, acc[4]);                                  \
  __builtin_amdgcn_s_setprio(0);                                            \
  __builtin_amdgcn_sched_barrier(0);                                        \
} while (0)

__global__ __launch_bounds__(256, 2) void gemm1_fused(
    const ushort* __restrict__ A, const ushort* __restrict__ W,
    const float* __restrict__ bias, ushort* __restrict__ A2F) {
  // LDS union: [0,30720) = 3 stage bufs (10KB each) during main loop;
  // epilogue reuses: hvt 80x68 f32 at 0 (21760B), outb at 21760 (32768B).
  __shared__ __align__(16) unsigned char ldsmem[54528];
  ushort* sbase = (ushort*)ldsmem;
  float (*hvt)[68] = (float(*)[68])ldsmem;
  ushort* outb = (ushort*)(ldsmem + 21760);

  const int tid = threadIdx.x;
  const int wave = tid >> 6, lane = tid & 63;
  const int lr = lane & 15, kg = lane >> 4;
  const int mx2 = blockIdx.x, ny = blockIdx.y;
  const int b = mx2 >> 1, half = mx2 & 1;
  const int rgA0 = 9 * b + 4 * half;          // first of 5 A row-groups
  const int n0 = ny * 64;
  const int ngw = ny * 4 + wave;              // W col-group for this wave

  // A staging unit assignment: unit u = g*2+s; waves 0,1 own {0..2},{3..5};
  // waves 2,3 own {6,7},{8,9}.
  const bool g3 = (wave < 2);
  const int uw = g3 ? wave * 3 : 6 + (wave - 2) * 2;
  const int u0 = uw, u1 = uw + 1, u2 = g3 ? uw + 2 : uw + 1;
  // global src base for unit u (elems; +kb*1024 per K-step):
  auto srcA = [&](int u) {
    return A + ((size_t)(rgA0 + (u >> 1)) * 32 + (u & 1)) * 512 + lane * 8;
  };
  const ushort* srcu0 = srcA(u0);
  const ushort* srcu1 = srcA(u1);
  const ushort* srcu2 = srcA(u2);

  const ushort* bW = W + (size_t)ngw * 16384 + lane * 8;

  f32x4 acc[5] = {};
  short8 w0h, w0l, w1h, w1l, w2h, w2l;

  // prologue: stage steps 0,1 (interleaved S,W so FIFO wait counts work)
  STAGEA(0, 0); GLOAD(w0h, bW);        GLOAD(w0l, bW + 512);
  STAGEA(1, 1); GLOAD(w1h, bW + 1024); GLOAD(w1l, bW + 1536);

#define STEP(k, j, jn, WH, WL, NWH, NWL)                                     \
  WAITW; __builtin_amdgcn_s_barrier();                                       \
  COMPJ2(j, WH, WL);                                                         \
  STAGEA(jn, (k) + 2);                                                       \
  GLOAD(NWH, bW + ((k) + 2) * 1024); GLOAD(NWL, bW + ((k) + 2) * 1024 + 512)

  STEP(0, 0, 2, w0h, w0l, w2h, w2l);
  STEP(1, 1, 0, w1h, w1l, w0h, w0l);
  STEP(2, 2, 1, w2h, w2l, w1h, w1l);
  STEP(3, 0, 2, w0h, w0l, w2h, w2l);
  STEP(4, 1, 0, w1h, w1l, w0h, w0l);
  STEP(5, 2, 1, w2h, w2l, w1h, w1l);
  STEP(6, 0, 2, w0h, w0l, w2h, w2l);
  STEP(7, 1, 0, w1h, w1l, w0h, w0l);
  STEP(8, 2, 1, w2h, w2l, w1h, w1l);
  STEP(9, 0, 2, w0h, w0l, w2h, w2l);
  STEP(10, 1, 0, w1h, w1l, w0h, w0l);
  STEP(11, 2, 1, w2h, w2l, w1h, w1l);
  STEP(12, 0, 2, w0h, w0l, w2h, w2l);
  STEP(13, 1, 0, w1h, w1l, w0h, w0l);
  // step 14: nothing left to issue
  WAITW; __builtin_amdgcn_s_barrier();
  COMPJ2(2, w2h, w2l);
  // step 15: final — drain
  WAITV(0); __builtin_amdgcn_s_barrier();
  COMPJ2(0, w0h, w0l);
#undef STEP

  __syncthreads();   // LDS reuse boundary (stage bufs -> hvt/outb)

  // ---- epilogue 1: tanh -> LDS f32 tile [80 rows][64 cols] ----
  const float bv = bias[n0 + wave * 16 + lr];
  #pragma unroll
  for (int fr = 0; fr < 5; ++fr)
    #pragma unroll
    for (int r = 0; r < 4; ++r)
      hvt[fr * 16 + kg * 4 + r][wave * 16 + lr] = tanh_fast(acc[fr][r] + bv);
  __syncthreads();

  // ---- epilogue 2: per-column 16-window sums + split -> outb units ----
  {
    const int col = tid & 63, q = tid >> 6;
    float hv[32];
    #pragma unroll
    for (int d = 0; d < 32; ++d) hv[d] = hvt[q * 16 + d][col];
    float win = 0.f;
    #pragma unroll
    for (int d = 0; d < 16; ++d) win += hv[d];

    const int su = ((q * 4 + (col >> 5)) * 2) * 512
                 + ((col >> 3) & 3) * 128 + (col & 7);
    const int wu = ((q * 4 + 2 + (col >> 5)) * 2) * 512
                 + ((col >> 3) & 3) * 128 + (col & 7);
    #pragma unroll
    for (int tt = 0; tt < 16; ++tt) {
      ushort hi, lo;
      split2(hv[16 + tt], hi, lo);
      outb[su + tt * 8]       = hi;
      outb[su + tt * 8 + 512] = lo;
      split2(win, hi, lo);
      outb[wu + tt * 8]       = hi;
      outb[wu + tt * 8 + 512] = lo;
      win += hv[16 + tt] - hv[tt];
    }
  }
  __syncthreads();

  // ---- epilogue 3: burst copy 32 units of 1KB to A2F ----
  const int rg20 = 4 * mx2;
  #pragma unroll
  for (int it = 0; it < 8; ++it) {
    const int lin = it * 2048 + tid * 8;
    const int u = lin >> 9, w = lin & 511;
    const int uq = u >> 3, ukbl = (u >> 1) & 3, us = u & 1;
    const int KB = (ukbl < 2) ? (2 * ny + ukbl) : (8 + 2 * ny + (ukbl - 2));
    const size_t dst = ((size_t)((rg20 + uq) * 16 + KB) * 2 + us) * 512 + w;
    *(short8*)(A2F + dst) = *(const short8*)(outb + lin);
  }
}

// ---------------------------------------------------------------------------
// gemm2 (R12 form): depth-4 asm pipeline, wave tile 32x32, fast tanh,
// row-major f32 out.
// ---------------------------------------------------------------------------
struct FB { short8 ah0, ah1, al0, al1, b10, b11, b20, b21; };

#define LOADI(Q, tt) do {                                                    \
  GLOAD(Q.ah0, baseA00 + (tt) * 1024);                                       \
  GLOAD(Q.ah1, baseA10 + (tt) * 1024);                                       \
  GLOAD(Q.al0, baseA01 + (tt) * 1024);                                       \
  GLOAD(Q.al1, baseA11 + (tt) * 1024);                                       \
  GLOAD(Q.b10, baseW0h + (tt) * 1024);                                       \
  GLOAD(Q.b11, baseW1h + (tt) * 1024);                                       \
  GLOAD(Q.b20, baseW0l + (tt) * 1024);                                       \
  GLOAD(Q.b21, baseW1l + (tt) * 1024);                                       \
} while (0)

#define COMP(Q) do {                                                         \
  __builtin_amdgcn_s_setprio(1);                                             \
  MF(Q.ah0, Q.b10, acc00); MF(Q.ah0, Q.b11, acc01);                          \
  MF(Q.ah1, Q.b10, acc10); MF(Q.ah1, Q.b11, acc11);                          \
  MF(Q.ah0, Q.b20, acc00); MF(Q.ah0, Q.b21, acc01);                          \
  MF(Q.ah1, Q.b20, acc10); MF(Q.ah1, Q.b21, acc11);                          \
  MF(Q.al0, Q.b10, acc00); MF(Q.al0, Q.b11, acc01);                          \
  MF(Q.al1, Q.b10, acc10); MF(Q.al1, Q.b11, acc11);                          \
  __builtin_amdgcn_s_setprio(0);                                             \
  __builtin_amdgcn_sched_barrier(0);                                         \
} while (0)

__global__ __launch_bounds__(256, 2) void gemm_mfma(
    const ushort* __restrict__ A, const ushort* __restrict__ W,
    const float* __restrict__ bias, float* __restrict__ out) {
  const int t = threadIdx.x;
  const int wave = t >> 6, lane = t & 63;
  const int lr = lane & 15, kg = lane >> 4;
  const int m0 = blockIdx.x * 64 + (wave >> 1) * 32;
  const int n0 = blockIdx.y * 64 + (wave & 1) * 32;
  const int rg0 = m0 >> 4, ng0 = n0 >> 4;

  const ushort* baseA00 = A + ((size_t)((rg0 + 0) * 32 + 0)) * 512 + lane * 8;
  const ushort* baseA01 = A + ((size_t)((rg0 + 0) * 32 + 1)) * 512 + lane * 8;
  const ushort* baseA10 = A + ((size_t)((rg0 + 1) * 32 + 0)) * 512 + lane * 8;
  const ushort* baseA11 = A + ((size_t)((rg0 + 1) * 32 + 1)) * 512 + lane * 8;
  const ushort* baseW0h = W + ((size_t)((ng0 + 0) * 32 + 0)) * 512 + lane * 8;
  const ushort* baseW0l = W + ((size_t)((ng0 + 0) * 32 + 1)) * 512 + lane * 8;
  const ushort* baseW1h = W + ((size_t)((ng0 + 1) * 32 + 0)) * 512 + lane * 8;
  const ushort* baseW1l = W + ((size_t)((ng0 + 1) * 32 + 1)) * 512 + lane * 8;

  f32x4 acc00 = {}, acc01 = {}, acc10 = {}, acc11 = {};
  FB q0, q1, q2, q3, q4;

  LOADI(q0, 0); LOADI(q1, 1); LOADI(q2, 2); LOADI(q3, 3); LOADI(q4, 4);
  WAITV(32); COMP(q0); LOADI(q0, 5);
  WAITV(32); COMP(q1); LOADI(q1, 6);
  WAITV(32); COMP(q2); LOADI(q2, 7);
  WAITV(32); COMP(q3); LOADI(q3, 8);
  WAITV(32); COMP(q4); LOADI(q4, 9);
  WAITV(32); COMP(q0); LOADI(q0, 10);
  WAITV(32); COMP(q1); LOADI(q1, 11);
  WAITV(32); COMP(q2); LOADI(q2, 12);
  WAITV(32); COMP(q3); LOADI(q3, 13);
  WAITV(32); COMP(q4); LOADI(q4, 14);
  WAITV(32); COMP(q0); LOADI(q0, 15);
  WAITV(32); COMP(q1);
  WAITV(24); COMP(q2);
  WAITV(16); COMP(q3);
  WAITV(8);  COMP(q4);
  WAITV(0);  COMP(q0);

  const float bv0 = bias[n0 + lr];
  const float bv1 = bias[n0 + 16 + lr];
  auto epi = [&](const f32x4& a, int mt, int nt, float bv) {
    #pragma unroll
    for (int r = 0; r < 4; ++r) {
      const int row = m0 + mt * 16 + kg * 4 + r;
      const int col = n0 + nt * 16 + lr;
      out[(size_t)row * FEATC + col] = tanh_fast(a[r] + bv);
    }
  };
  epi(acc00, 0, 0, bv0);
  epi(acc01, 0, 1, bv1);
  epi(acc10, 1, 0, bv0);
  epi(acc11, 1, 1, bv1);
}

}  // namespace

extern "C" void kernel_launch(void* const* d_in, const int* in_sizes, int n_in,
                              void* d_out, int out_size, void* d_ws, size_t ws_size,
                              hipStream_t stream) {
  const float* x     = (const float*)d_in[0];
  const float* nodes = (const float*)d_in[1];
  // d_in[2] = edge_weight: forward value ew/ew == 1.0 -> unused.
  const float* W1s = (const float*)d_in[3];
  const float* W1n = (const float*)d_in[4];
  const float* b1  = (const float*)d_in[5];
  const float* W2s = (const float*)d_in[6];
  const float* W2n = (const float*)d_in[7];
  const float* b2  = (const float*)d_in[8];
  float* out = (float*)d_out;

  // workspace (ushort): A1F + A2F + WF1 + WF2 = 36.7 MB
  const size_t a1_sz = (size_t)BQ * M1 * 1024;      // 9,437,184
  const size_t a2_sz = (size_t)BQ * M2 * 1024;      // 8,388,608
  const size_t wf_sz = (size_t)16 * 16 * 2 * 512;   // 262,144 per layer
  const size_t need = (a1_sz + a2_sz + 2 * wf_sz) * sizeof(ushort);
  if (ws_size < need) return;

  ushort* p = (ushort*)d_ws;
  ushort* A1F = p; p += a1_sz;
  ushort* A2F = p; p += a2_sz;
  ushort* WF1 = p; p += wf_sz;
  ushort* WF2 = p; p += wf_sz;

  prep_fused<<<640, 256, 0, stream>>>(x, nodes, W1s, W1n, W2s, W2n,
                                      A1F, WF1, WF2);
  gemm1_fused<<<dim3(BQ * 2, FEATC / 64), 256, 0, stream>>>(A1F, WF1, b1, A2F);
  gemm_mfma<<<dim3((BQ * M2) / 64, FEATC / 64), 256, 0, stream>>>(
      A2F, WF2, b2, out);
}

// Round 15
// 35.842 us; speedup vs baseline: 1.1642x; 1.0426x over previous
//
#include <hip/hip_runtime.h>
#include <hip/hip_bf16.h>

// SparseGCM: 2-layer causal-window GCN on MI355X — split-bf16, fragment-
// contiguous layout, 3-kernel chain, BOTH gemms with LDS-shared A:
//   prep_fused -> gemm1_fused (LDS-A + halo winsum epilogue) -> gemm2_lds.
//
// Edges are j->i for j in [i-16,i) per batch, weights normalize to 1.0 ->
// "gather+segment_sum" == 16-wide sliding-window sum. Only outputs i in
// [512,640) matter: layer1 computes i in [496,640).
//
// Precision (R2/R4): single-bf16 fails (correlated L1 errors x16-amplified by
// the L2 window sum). Split v = hi+lo bf16; compute Ahi*Whi + Ahi*Wlo +
// Alo*Whi (3 MFMAs) ~= fp32. Validated R5-R14 (absmax 0.0039).
//
// Perf history: R5 61.2; R6 99.5; R7 55.8; R8 49.7; R9 ABORT (compiler reg
// loads inside asm-vmcnt region); R10 47.8; R11 45.5; R12 41.2; R13 41.7
// (SBAR-only NEUTRAL); R14 37.4 (gemm1 LDS-shared A: per-CU VMEM redundancy
// was the limiter; gl_lds builtin + counted asm vmcnt + raw barrier works).
// R15: same treatment for gemm2 — wave = 16-col strip x 64 rows, A staged
// once/block (8x1KB units/step, 2/wave, uniform vmcnt(4)), triple-buffered,
// depth-2, vmcnt(0) only at the last step. Block VMEM 512KB -> 256KB.

namespace {

constexpr int BQ    = 64;
constexpr int FEATC = 256;
constexpr int M1 = 144;   // layer-1 rows/batch: i in [496,640)
constexpr int M2 = 128;   // layer-2 rows/batch: i in [512,640)

using ushort = unsigned short;
using short8 = __attribute__((ext_vector_type(8))) short;   // 8 bf16
using f32x4  = __attribute__((ext_vector_type(4))) float;

__device__ __forceinline__ ushort f2bf(float f) {  // RNE
  union { float f; unsigned u; } v{f};
  unsigned r = v.u + 0x7FFFu + ((v.u >> 16) & 1u);
  return (ushort)(r >> 16);
}
__device__ __forceinline__ float bf2f(ushort h) {
  union { unsigned u; float f; } v{(unsigned)h << 16};
  return v.f;
}
__device__ __forceinline__ void split2(float v, ushort& hi, ushort& lo) {
  hi = f2bf(v);
  lo = f2bf(v - bf2f(hi));
}
// tanh(x) = 1 - 2/(1 + exp2(2*log2e*x)); exp2/rcp handle the limits.
__device__ __forceinline__ float tanh_fast(float x) {
  const float e = __builtin_amdgcn_exp2f(x * 2.8853900817779268f);
  return 1.0f - 2.0f * __builtin_amdgcn_rcpf(1.0f + e);
}
__device__ __forceinline__ void gl_lds16(const ushort* g, ushort* l) {
  __builtin_amdgcn_global_load_lds(
      (const __attribute__((address_space(1))) void*)g,
      (__attribute__((address_space(3))) void*)l, 16, 0, 0);
}

// Fragment-contiguous layout. Row r, packed k in [0,512) ([self|win] for A,
// [Wself|Wnbr] for W), s = hi(0)/lo(1) (for W: W1/W2). A wave's MFMA fragment
// = contiguous 1KB block at ((rg*16 + kb)*2 + s)*512, lane-linear inside.
__device__ __forceinline__ size_t frag_idx(int row, int k, int s) {
  return ((size_t)(((row >> 4) * 16 + (k >> 5)) * 2 + s)) * 512
       + ((k >> 3) & 3) * 128 + (row & 15) * 8 + (k & 7);
}
// Same, local to one 16-row group (16384-elem block).
__device__ __forceinline__ int lofs(int row_l, int k, int s) {
  return ((k >> 5) * 2 + s) * 512 + ((k >> 3) & 3) * 128 + row_l * 8 + (k & 7);
}

// ---------------------------------------------------------------------------
// prep_fused: blocks [0,576) = prep1 (A1F via LDS burst, XCD-permuted);
//             blocks [576,640) = weight transpose+split.
// ---------------------------------------------------------------------------
__global__ __launch_bounds__(256) void prep_fused(
    const float* __restrict__ x, const float* __restrict__ nodes,
    const float* __restrict__ W1s, const float* __restrict__ W1n,
    const float* __restrict__ W2s, const float* __restrict__ W2n,
    ushort* __restrict__ A1F, ushort* __restrict__ WF1,
    ushort* __restrict__ WF2) {
  __shared__ ushort lds_o[16384];   // one 16-row frag group (32 KB)
  __shared__ float tile[64][65];
  const int blk = blockIdx.x;
  if (blk < 576) {
    const int G = 4 * (blk % 144) + (blk / 144);   // XCD spread permutation
    const int b = G / 9, c = G % 9, f = threadIdx.x;
    const int t0 = c * 16, i0 = 496 + t0;
    const float* nb = nodes + ((size_t)b * 640) * FEATC + f;
    const float* xb = x     + ((size_t)b * 128) * FEATC + f;

    float v[32];
    #pragma unroll
    for (int d = 0; d < 32; ++d) {
      const int i = i0 - 16 + d;
      v[d] = (i < 512) ? nb[(size_t)i * FEATC] : xb[(size_t)(i - 512) * FEATC];
    }
    float win = 0.f;
    #pragma unroll
    for (int d = 0; d < 16; ++d) win += v[d];

    #pragma unroll
    for (int tt = 0; tt < 16; ++tt) {
      ushort hi, lo;
      split2(v[16 + tt], hi, lo);
      lds_o[lofs(tt, f, 0)] = hi;
      lds_o[lofs(tt, f, 1)] = lo;
      split2(win, hi, lo);
      lds_o[lofs(tt, 256 + f, 0)] = hi;
      lds_o[lofs(tt, 256 + f, 1)] = lo;
      win += v[16 + tt] - v[tt];
    }
    __syncthreads();
    ushort* dst = A1F + (size_t)G * 16384;
    #pragma unroll
    for (int it = 0; it < 8; ++it) {
      const int idx = it * 256 + threadIdx.x;
      *(short8*)(dst + idx * 8) = *(const short8*)(lds_o + idx * 8);
    }
  } else {
    const int w = blk - 576;
    const int z = w >> 4, rem = w & 15;
    const int k0 = (rem >> 2) * 64, n0 = (rem & 3) * 64;
    const float* src = (z == 0) ? W1s : (z == 1) ? W1n : (z == 2) ? W2s : W2n;
    ushort* dst = (z < 2) ? WF1 : WF2;
    const int koff = (z & 1) * 256;
    const int c = threadIdx.x & 63, r4 = threadIdx.x >> 6;
    #pragma unroll
    for (int p = 0; p < 16; ++p) {
      const int k = r4 + p * 4;
      tile[k][c] = src[(size_t)(k0 + k) * FEATC + n0 + c];
    }
    __syncthreads();
    #pragma unroll
    for (int p = 0; p < 16; ++p) {
      const int n = r4 + p * 4;
      ushort hi, lo;
      split2(tile[c][n], hi, lo);
      dst[frag_idx(n0 + n, koff + k0 + c, 0)] = hi;   // W1 (hi) slot
      dst[frag_idx(n0 + n, koff + k0 + c, 1)] = lo;   // W2 (lo) slot
    }
  }
}

// ---------------------------------------------------------------------------
// Shared asm helpers. Rules: only asm vmem / gl_lds builtin inside pipelined
// regions; counted vmcnt via asm; raw barrier via builtin (no drain).
// ---------------------------------------------------------------------------
#define GLOAD(dst, ptr)                                                      \
  asm volatile("global_load_dwordx4 %0, %1, off"                             \
               : "=v"(dst) : "v"(ptr) : "memory")

#define WAITV(n) do {                                                        \
  asm volatile("s_waitcnt vmcnt(" #n ")" ::: "memory");                      \
  __builtin_amdgcn_sched_barrier(0);                                         \
} while (0)

#define MF(a, b, c) c = __builtin_amdgcn_mfma_f32_16x16x32_bf16(a, b, c, 0, 0, 0)

// ---------------------------------------------------------------------------
// gemm1_fused (R14-validated): 80-row h1 window (16-row halo), A staged in
// LDS once per block, triple-buffered depth-2; W per-wave asm rotation.
// Winsum epilogue emits A2F fragment groups (LDS reused).
// ---------------------------------------------------------------------------
#define STAGEA(jn, kb) do {                                                  \
  gl_lds16(srcu0 + (kb) * 1024, sbase + (jn) * 5120 + u0 * 512);             \
  gl_lds16(srcu1 + (kb) * 1024, sbase + (jn) * 5120 + u1 * 512);             \
  if (g3) gl_lds16(srcu2 + (kb) * 1024, sbase + (jn) * 5120 + u2 * 512);     \
} while (0)

#define WAITW do { if (g3) { WAITV(5); } else { WAITV(4); } } while (0)

#define COMPJ2(j, WH, WL) do {                                               \
  const ushort* bp_ = sbase + (j) * 5120 + lane * 8;                         \
  const short8 a0h = *(const short8*)(bp_ + 0 * 512);                        \
  const short8 a0l = *(const short8*)(bp_ + 1 * 512);                        \
  const short8 a1h = *(const short8*)(bp_ + 2 * 512);                        \
  const short8 a1l = *(const short8*)(bp_ + 3 * 512);                        \
  const short8 a2h = *(const short8*)(bp_ + 4 * 512);                        \
  const short8 a2l = *(const short8*)(bp_ + 5 * 512);                        \
  const short8 a3h = *(const short8*)(bp_ + 6 * 512);                        \
  const short8 a3l = *(const short8*)(bp_ + 7 * 512);                        \
  const short8 a4h = *(const short8*)(bp_ + 8 * 512);                        \
  const short8 a4l = *(const short8*)(bp_ + 9 * 512);                        \
  __builtin_amdgcn_s_setprio(1);                                            \
  MF(a0h, WH, acc[0]); MF(a1h, WH, acc[1]); MF(a2h, WH, acc[2]);             \
  MF(a3h, WH, acc[3]); MF(a4h, WH, acc[4]);                                  \
  MF(a0h, WL, acc[0]); MF(a1h, WL, acc[1]); MF(a2h, WL, acc[2]);             \
  MF(a3h, WL, acc[3]); MF(a4h, WL, acc[4]);                                  \
  MF(a0l, WH, acc[0]); MF(a1l, WH, acc[1]); MF(a2l, WH, acc[2]);             \
  MF(a3l, WH, acc[3]); MF(a4l, WH, acc[4]);                                  \
  __builtin_amdgcn_s_setprio(0);                                            \
  __builtin_amdgcn_sched_barrier(0);                                        \
} while (0)

__global__ __launch_bounds__(256, 2) void gemm1_fused(
    const ushort* __restrict__ A, const ushort* __restrict__ W,
    const float* __restrict__ bias, ushort* __restrict__ A2F) {
  // LDS union: [0,30720) = 3 stage bufs (10KB each) during main loop;
  // epilogue reuses: hvt 80x68 f32 at 0 (21760B), outb at 21760 (32768B).
  __shared__ __align__(16) unsigned char ldsmem[54528];
  ushort* sbase = (ushort*)ldsmem;
  float (*hvt)[68] = (float(*)[68])ldsmem;
  ushort* outb = (ushort*)(ldsmem + 21760);

  const int tid = threadIdx.x;
  const int wave = tid >> 6, lane = tid & 63;
  const int lr = lane & 15, kg = lane >> 4;
  const int mx2 = blockIdx.x, ny = blockIdx.y;
  const int b = mx2 >> 1, half = mx2 & 1;
  const int rgA0 = 9 * b + 4 * half;          // first of 5 A row-groups
  const int n0 = ny * 64;
  const int ngw = ny * 4 + wave;              // W col-group for this wave

  // A staging unit assignment: unit u = g*2+s; waves 0,1 own {0..2},{3..5};
  // waves 2,3 own {6,7},{8,9}.
  const bool g3 = (wave < 2);
  const int uw = g3 ? wave * 3 : 6 + (wave - 2) * 2;
  const int u0 = uw, u1 = uw + 1, u2 = g3 ? uw + 2 : uw + 1;
  auto srcA = [&](int u) {
    return A + ((size_t)(rgA0 + (u >> 1)) * 32 + (u & 1)) * 512 + lane * 8;
  };
  const ushort* srcu0 = srcA(u0);
  const ushort* srcu1 = srcA(u1);
  const ushort* srcu2 = srcA(u2);

  const ushort* bW = W + (size_t)ngw * 16384 + lane * 8;

  f32x4 acc[5] = {};
  short8 w0h, w0l, w1h, w1l, w2h, w2l;

  // prologue: stage steps 0,1 (interleaved S,W so FIFO wait counts work)
  STAGEA(0, 0); GLOAD(w0h, bW);        GLOAD(w0l, bW + 512);
  STAGEA(1, 1); GLOAD(w1h, bW + 1024); GLOAD(w1l, bW + 1536);

#define STEP(k, j, jn, WH, WL, NWH, NWL)                                     \
  WAITW; __builtin_amdgcn_s_barrier();                                       \
  COMPJ2(j, WH, WL);                                                         \
  STAGEA(jn, (k) + 2);                                                       \
  GLOAD(NWH, bW + ((k) + 2) * 1024); GLOAD(NWL, bW + ((k) + 2) * 1024 + 512)

  STEP(0, 0, 2, w0h, w0l, w2h, w2l);
  STEP(1, 1, 0, w1h, w1l, w0h, w0l);
  STEP(2, 2, 1, w2h, w2l, w1h, w1l);
  STEP(3, 0, 2, w0h, w0l, w2h, w2l);
  STEP(4, 1, 0, w1h, w1l, w0h, w0l);
  STEP(5, 2, 1, w2h, w2l, w1h, w1l);
  STEP(6, 0, 2, w0h, w0l, w2h, w2l);
  STEP(7, 1, 0, w1h, w1l, w0h, w0l);
  STEP(8, 2, 1, w2h, w2l, w1h, w1l);
  STEP(9, 0, 2, w0h, w0l, w2h, w2l);
  STEP(10, 1, 0, w1h, w1l, w0h, w0l);
  STEP(11, 2, 1, w2h, w2l, w1h, w1l);
  STEP(12, 0, 2, w0h, w0l, w2h, w2l);
  STEP(13, 1, 0, w1h, w1l, w0h, w0l);
  WAITW; __builtin_amdgcn_s_barrier();
  COMPJ2(2, w2h, w2l);
  WAITV(0); __builtin_amdgcn_s_barrier();
  COMPJ2(0, w0h, w0l);
#undef STEP

  __syncthreads();   // LDS reuse boundary (stage bufs -> hvt/outb)

  // ---- epilogue 1: tanh -> LDS f32 tile [80 rows][64 cols] ----
  const float bv = bias[n0 + wave * 16 + lr];
  #pragma unroll
  for (int fr = 0; fr < 5; ++fr)
    #pragma unroll
    for (int r = 0; r < 4; ++r)
      hvt[fr * 16 + kg * 4 + r][wave * 16 + lr] = tanh_fast(acc[fr][r] + bv);
  __syncthreads();

  // ---- epilogue 2: per-column 16-window sums + split -> outb units ----
  {
    const int col = tid & 63, q = tid >> 6;
    float hv[32];
    #pragma unroll
    for (int d = 0; d < 32; ++d) hv[d] = hvt[q * 16 + d][col];
    float win = 0.f;
    #pragma unroll
    for (int d = 0; d < 16; ++d) win += hv[d];

    const int su = ((q * 4 + (col >> 5)) * 2) * 512
                 + ((col >> 3) & 3) * 128 + (col & 7);
    const int wu = ((q * 4 + 2 + (col >> 5)) * 2) * 512
                 + ((col >> 3) & 3) * 128 + (col & 7);
    #pragma unroll
    for (int tt = 0; tt < 16; ++tt) {
      ushort hi, lo;
      split2(hv[16 + tt], hi, lo);
      outb[su + tt * 8]       = hi;
      outb[su + tt * 8 + 512] = lo;
      split2(win, hi, lo);
      outb[wu + tt * 8]       = hi;
      outb[wu + tt * 8 + 512] = lo;
      win += hv[16 + tt] - hv[tt];
    }
  }
  __syncthreads();

  // ---- epilogue 3: burst copy 32 units of 1KB to A2F ----
  const int rg20 = 4 * mx2;
  #pragma unroll
  for (int it = 0; it < 8; ++it) {
    const int lin = it * 2048 + tid * 8;
    const int u = lin >> 9, w = lin & 511;
    const int uq = u >> 3, ukbl = (u >> 1) & 3, us = u & 1;
    const int KB = (ukbl < 2) ? (2 * ny + ukbl) : (8 + 2 * ny + (ukbl - 2));
    const size_t dst = ((size_t)((rg20 + uq) * 16 + KB) * 2 + us) * 512 + w;
    *(short8*)(A2F + dst) = *(const short8*)(outb + lin);
  }
}

// ---------------------------------------------------------------------------
// gemm2_lds (R15): mirror of gemm1's LDS-A structure, no halo.
// Grid (128, 4). Wave = 16-col W strip x 64 rows (4 row-frags, 12 MFMA/step).
// A staged once/block: 8 units of 1KB per K-step, 2 units/wave (uniform).
// Triple-buffered (24KB), depth-2, vmcnt(4) steady, vmcnt(0) last step only.
// ---------------------------------------------------------------------------
#define STAGE2(jn, kb) do {                                                  \
  gl_lds16(srcv0 + (kb) * 1024, sb2 + (jn) * 4096 + v0 * 512);               \
  gl_lds16(srcv1 + (kb) * 1024, sb2 + (jn) * 4096 + v1 * 512);               \
} while (0)

#define COMPK(j, WH, WL) do {                                                \
  const ushort* bp_ = sb2 + (j) * 4096 + lane * 8;                           \
  const short8 a0h = *(const short8*)(bp_ + 0 * 512);                        \
  const short8 a0l = *(const short8*)(bp_ + 1 * 512);                        \
  const short8 a1h = *(const short8*)(bp_ + 2 * 512);                        \
  const short8 a1l = *(const short8*)(bp_ + 3 * 512);                        \
  const short8 a2h = *(const short8*)(bp_ + 4 * 512);                        \
  const short8 a2l = *(const short8*)(bp_ + 5 * 512);                        \
  const short8 a3h = *(const short8*)(bp_ + 6 * 512);                        \
  const short8 a3l = *(const short8*)(bp_ + 7 * 512);                        \
  __builtin_amdgcn_s_setprio(1);                                            \
  MF(a0h, WH, acc[0]); MF(a1h, WH, acc[1]);                                  \
  MF(a2h, WH, acc[2]); MF(a3h, WH, acc[3]);                                  \
  MF(a0h, WL, acc[0]); MF(a1h, WL, acc[1]);                                  \
  MF(a2h, WL, acc[2]); MF(a3h, WL, acc[3]);                                  \
  MF(a0l, WH, acc[0]); MF(a1l, WH, acc[1]);                                  \
  MF(a2l, WH, acc[2]); MF(a3l, WH, acc[3]);                                  \
  __builtin_amdgcn_s_setprio(0);                                            \
  __builtin_amdgcn_sched_barrier(0);                                        \
} while (0)

__global__ __launch_bounds__(256, 2) void gemm2_lds(
    const ushort* __restrict__ A, const ushort* __restrict__ W,
    const float* __restrict__ bias, float* __restrict__ out) {
  __shared__ __align__(16) ushort sb2[3 * 4096];   // 24 KB

  const int tid = threadIdx.x;
  const int wave = tid >> 6, lane = tid & 63;
  const int lr = lane & 15, kg = lane >> 4;
  const int mx = blockIdx.x, ny = blockIdx.y;
  const int rg0 = mx * 4;                     // 4 A row-groups (64 rows)
  const int ngw = ny * 4 + wave;              // W col-group for this wave
  const int n0col = ngw * 16;

  const int v0 = wave * 2, v1 = wave * 2 + 1; // A staging units
  auto srcA = [&](int u) {
    return A + ((size_t)(rg0 + (u >> 1)) * 32 + (u & 1)) * 512 + lane * 8;
  };
  const ushort* srcv0 = srcA(v0);
  const ushort* srcv1 = srcA(v1);
  const ushort* bW = W + (size_t)ngw * 16384 + lane * 8;

  f32x4 acc[4] = {};
  short8 w0h, w0l, w1h, w1l, w2h, w2l;

  STAGE2(0, 0); GLOAD(w0h, bW);        GLOAD(w0l, bW + 512);
  STAGE2(1, 1); GLOAD(w1h, bW + 1024); GLOAD(w1l, bW + 1536);

#define STEP2(k, j, jn, WH, WL, NWH, NWL)                                    \
  WAITV(4); __builtin_amdgcn_s_barrier();                                    \
  COMPK(j, WH, WL);                                                          \
  STAGE2(jn, (k) + 2);                                                       \
  GLOAD(NWH, bW + ((k) + 2) * 1024); GLOAD(NWL, bW + ((k) + 2) * 1024 + 512)

  STEP2(0, 0, 2, w0h, w0l, w2h, w2l);
  STEP2(1, 1, 0, w1h, w1l, w0h, w0l);
  STEP2(2, 2, 1, w2h, w2l, w1h, w1l);
  STEP2(3, 0, 2, w0h, w0l, w2h, w2l);
  STEP2(4, 1, 0, w1h, w1l, w0h, w0l);
  STEP2(5, 2, 1, w2h, w2l, w1h, w1l);
  STEP2(6, 0, 2, w0h, w0l, w2h, w2l);
  STEP2(7, 1, 0, w1h, w1l, w0h, w0l);
  STEP2(8, 2, 1, w2h, w2l, w1h, w1l);
  STEP2(9, 0, 2, w0h, w0l, w2h, w2l);
  STEP2(10, 1, 0, w1h, w1l, w0h, w0l);
  STEP2(11, 2, 1, w2h, w2l, w1h, w1l);
  STEP2(12, 0, 2, w0h, w0l, w2h, w2l);
  STEP2(13, 1, 0, w1h, w1l, w0h, w0l);
  WAITV(4); __builtin_amdgcn_s_barrier();
  COMPK(2, w2h, w2l);
  WAITV(0); __builtin_amdgcn_s_barrier();
  COMPK(0, w0h, w0l);
#undef STEP2

  // epilogue: bias + fast tanh, row-major f32 out (compiler vmem after drain)
  const float bv = bias[n0col + lr];
  #pragma unroll
  for (int fr = 0; fr < 4; ++fr)
    #pragma unroll
    for (int r = 0; r < 4; ++r) {
      const int row = mx * 64 + fr * 16 + kg * 4 + r;
      out[(size_t)row * FEATC + n0col + lr] = tanh_fast(acc[fr][r] + bv);
    }
}

}  // namespace

extern "C" void kernel_launch(void* const* d_in, const int* in_sizes, int n_in,
                              void* d_out, int out_size, void* d_ws, size_t ws_size,
                              hipStream_t stream) {
  const float* x     = (const float*)d_in[0];
  const float* nodes = (const float*)d_in[1];
  // d_in[2] = edge_weight: forward value ew/ew == 1.0 -> unused.
  const float* W1s = (const float*)d_in[3];
  const float* W1n = (const float*)d_in[4];
  const float* b1  = (const float*)d_in[5];
  const float* W2s = (const float*)d_in[6];
  const float* W2n = (const float*)d_in[7];
  const float* b2  = (const float*)d_in[8];
  float* out = (float*)d_out;

  // workspace (ushort): A1F + A2F + WF1 + WF2 = 36.7 MB
  const size_t a1_sz = (size_t)BQ * M1 * 1024;      // 9,437,184
  const size_t a2_sz = (size_t)BQ * M2 * 1024;      // 8,388,608
  const size_t wf_sz = (size_t)16 * 16 * 2 * 512;   // 262,144 per layer
  const size_t need = (a1_sz + a2_sz + 2 * wf_sz) * sizeof(ushort);
  if (ws_size < need) return;

  ushort* p = (ushort*)d_ws;
  ushort* A1F = p; p += a1_sz;
  ushort* A2F = p; p += a2_sz;
  ushort* WF1 = p; p += wf_sz;
  ushort* WF2 = p; p += wf_sz;

  prep_fused<<<640, 256, 0, stream>>>(x, nodes, W1s, W1n, W2s, W2n,
                                      A1F, WF1, WF2);
  gemm1_fused<<<dim3(BQ * 2, FEATC / 64), 256, 0, stream>>>(A1F, WF1, b1, A2F);
  gemm2_lds<<<dim3((BQ * M2) / 64, FEATC / 64), 256, 0, stream>>>(
      A2F, WF2, b2, out);
}